// Round 14
// baseline (310.382 us; speedup 1.0000x reference)
//
#include <hip/hip_runtime.h>

#define NN 100000
#define DD 128
#define EE 640000
#define NPAD 100352   // NN rounded up to 256 multiple
#define NCHUNK 391    // (NN+255)/256
#define NREP 8        // histogram/cursor replicas

typedef __bf16 bf16x8 __attribute__((ext_vector_type(8)));
typedef float floatx4 __attribute__((ext_vector_type(4)));

union BF8 {
    bf16x8 v;
    unsigned short u[8];
    int4 i4;
};

__device__ __forceinline__ unsigned short f2bf(float f) {
    unsigned int u = __float_as_uint(f);
    u += 0x7FFF + ((u >> 16) & 1);   // round-to-nearest-even
    return (unsigned short)(u >> 16);
}

__device__ __forceinline__ float bf2f(unsigned short h) {
    return __uint_as_float(((unsigned int)h) << 16);
}

// ---------------------------------------------------------------------------
// Pure histogram (round-14: UNFUSED from the x-convert. Round-13 showed the
// fused kernel's 77MB streaming traffic evicted the hot histogram lines —
// 19.4MB of write-backs on a 3.2MB histogram — forcing atomics to HBM
// latency. Replication alone changed nothing; separation is the fix.)
// ---------------------------------------------------------------------------
__global__ __launch_bounds__(256) void hist_k(const int* __restrict__ ei,
                                              int* __restrict__ degr) {
    int e = blockIdx.x * 256 + threadIdx.x;       // EE = 2500*256 exactly
    atomicAdd(&degr[(blockIdx.x & (NREP - 1)) * NPAD + ei[EE + e]], 1);
}

// x fp32 -> bf16, 4 independent load/store pairs per thread (the round-12/13
// fused version had 1 dependent pair per thread -> latency-bound 1.8 TB/s).
__global__ __launch_bounds__(256) void convert_k(const float4* __restrict__ x4,
                                                 ushort4* __restrict__ xbf) {
    int base = blockIdx.x * 1024 + threadIdx.x;   // 3125*1024 = 3.2M exactly
    float4 v0 = x4[base];
    float4 v1 = x4[base + 256];
    float4 v2 = x4[base + 512];
    float4 v3 = x4[base + 768];
    ushort4 u0, u1, u2, u3;
    u0.x = f2bf(v0.x); u0.y = f2bf(v0.y); u0.z = f2bf(v0.z); u0.w = f2bf(v0.w);
    u1.x = f2bf(v1.x); u1.y = f2bf(v1.y); u1.z = f2bf(v1.z); u1.w = f2bf(v1.w);
    u2.x = f2bf(v2.x); u2.y = f2bf(v2.y); u2.z = f2bf(v2.z); u2.w = f2bf(v2.w);
    u3.x = f2bf(v3.x); u3.y = f2bf(v3.y); u3.z = f2bf(v3.z); u3.w = f2bf(v3.w);
    xbf[base] = u0;
    xbf[base + 256] = u1;
    xbf[base + 512] = u2;
    xbf[base + 768] = u3;
}

// Single-pass exclusive scan over NN total degrees (sum of NREP replicas);
// precomputes per-replica cursor bases (esort uses the same block&7 mapping,
// so per-replica slot counts match exactly). Wave-parallel lookback
// (round-8 lesson: single-thread walk = 106us serial chain).
__global__ __launch_bounds__(256) void scanlb_k(
    int* __restrict__ degr, unsigned int* __restrict__ descr,
    int* __restrict__ offs, int* __restrict__ curr) {
    __shared__ int s[256];
    __shared__ int sbase;
    const int c = blockIdx.x, t = threadIdx.x;
    int g = c * 256 + t;
    int dr[NREP];
    int v = 0;
    if (g < NN) {
#pragma unroll
        for (int r = 0; r < NREP; ++r) {
            dr[r] = degr[r * NPAD + g];
            v += dr[r];
        }
    } else {
#pragma unroll
        for (int r = 0; r < NREP; ++r) dr[r] = 0;
    }
    s[t] = v;
    __syncthreads();
    for (int off = 1; off < 256; off <<= 1) {
        int u = (t >= off) ? s[t - off] : 0;
        __syncthreads();
        s[t] += u;
        __syncthreads();
    }
    const int total = s[255];
    if (c == 0) {
        if (t == 0) {
            __hip_atomic_store(&descr[0], (2u << 30) | (unsigned)total,
                               __ATOMIC_RELEASE, __HIP_MEMORY_SCOPE_AGENT);
            sbase = 0;
        }
    } else if (t < 64) {
        if (t == 0)
            __hip_atomic_store(&descr[c], (1u << 30) | (unsigned)total,
                               __ATOMIC_RELEASE, __HIP_MEMORY_SCOPE_AGENT);
        int acc = 0;
        int base = c - 1;              // lane l inspects block (base - l)
        while (true) {
            int p = base - t;
            unsigned st = (p >= 0)
                ? __hip_atomic_load(&descr[p], __ATOMIC_ACQUIRE,
                                    __HIP_MEMORY_SCOPE_AGENT)
                : (2u << 30);          // virtual block -1: prefix 0
            unsigned fl = st >> 30;
            unsigned long long b2 = __ballot(fl == 2u);
            unsigned long long b0 = __ballot(fl == 0u);
            int l2 = b2 ? (__ffsll(b2) - 1) : 64;   // nearest inclusive-prefix
            int l0 = b0 ? (__ffsll(b0) - 1) : 64;   // nearest unpublished
            if (l0 < l2) continue;     // blocked by an empty slot: retry
            unsigned contrib = (t <= l2) ? (st & 0x3FFFFFFFu) : 0u;
#pragma unroll
            for (int o2 = 32; o2 > 0; o2 >>= 1)
                contrib += __shfl_down(contrib, o2, 64);
            contrib = __shfl(contrib, 0, 64);
            acc += (int)contrib;
            if (l2 < 64) break;        // absorbed an inclusive prefix
            base -= 64;                // all aggregates: step back a window
        }
        if (t == 0) {
            sbase = acc;
            __hip_atomic_store(&descr[c], (2u << 30) | (unsigned)(acc + total),
                               __ATOMIC_RELEASE, __HIP_MEMORY_SCOPE_AGENT);
        }
    }
    __syncthreads();
    if (g < NN) {
        int o = sbase + s[t] - v;   // exclusive prefix
        offs[g] = o;
        int running = o;
#pragma unroll
        for (int r = 0; r < NREP; ++r) {
            curr[r * NPAD + g] = running;
            running += dr[r];
        }
        degr[g] = v;   // total degree for aggregate (replica-0 slot reused)
    }
}

// esort (blocks 0..2499; replica = b&7 matches hist) + folded-in W
// fp32->bf16 preconvert and stats zeroing (blocks 2500..2531).
__global__ __launch_bounds__(256) void esort_k(
    const int* __restrict__ ei, int* __restrict__ curr,
    int* __restrict__ ssrc, const float* __restrict__ W1,
    const float* __restrict__ W2, unsigned short* __restrict__ wbf,
    float* __restrict__ stats) {
    int b = blockIdx.x;
    if (b >= 2500) {
        int i = (b - 2500) * 256 + threadIdx.x;   // 0..8191 float4 units
        if (b == 2500) {
            stats[threadIdx.x] = 0.f;
            stats[256 + threadIdx.x] = 0.f;
        }
        const float4* s4 = (i < 4096) ? (const float4*)W1 : (const float4*)W2;
        float4 v = s4[i & 4095];
        ushort4 u;
        u.x = f2bf(v.x); u.y = f2bf(v.y); u.z = f2bf(v.z); u.w = f2bf(v.w);
        ((ushort4*)wbf)[i] = u;
        return;
    }
    int e = b * 256 + threadIdx.x;
    int pos = atomicAdd(&curr[(b & (NREP - 1)) * NPAD + ei[EE + e]], 1);
    ssrc[pos] = ei[e];
}

// ---------------------------------------------------------------------------
// aggregate + fuse: h[node] = bf16((1+eps)*x[node] + sum_{src in CSR} x[src])
// Gathers from the bf16 x copy (256B rows, 25.6MB working set); 8-wide
// predicated unroll; 12500 independent blocks.
// ---------------------------------------------------------------------------
__global__ __launch_bounds__(256, 4) void aggregate_k(
    const ushort4* __restrict__ xb, const int* __restrict__ ssrc,
    const int* __restrict__ offs, const int* __restrict__ deg,
    const float* __restrict__ epsp, ushort4* __restrict__ hout) {
    int tid = blockIdx.x * 256 + threadIdx.x;
    int node = tid >> 5, lane = tid & 31;
    if (node >= NN) return;
    int start = offs[node], d = deg[node];
    float ef = 1.0f + epsp[0];
    ushort4 ov = xb[node * 32 + lane];
    float ax = ef * bf2f(ov.x), ay = ef * bf2f(ov.y);
    float az = ef * bf2f(ov.z), aw = ef * bf2f(ov.w);
    for (int j = 0; j < d; j += 8) {
        int r = d - j;          // >= 1
        int b = start + j;
        int s0 = ssrc[b];
        int s1 = ssrc[b + ((r > 1) ? 1 : 0)];
        int s2 = ssrc[b + ((r > 2) ? 2 : 0)];
        int s3 = ssrc[b + ((r > 3) ? 3 : 0)];
        int s4i = ssrc[b + ((r > 4) ? 4 : 0)];
        int s5 = ssrc[b + ((r > 5) ? 5 : 0)];
        int s6 = ssrc[b + ((r > 6) ? 6 : 0)];
        int s7 = ssrc[b + ((r > 7) ? 7 : 0)];
        ushort4 x0 = xb[s0 * 32 + lane];
        ushort4 x1 = xb[s1 * 32 + lane];
        ushort4 x2 = xb[s2 * 32 + lane];
        ushort4 x3 = xb[s3 * 32 + lane];
        ushort4 x4v = xb[s4i * 32 + lane];
        ushort4 x5 = xb[s5 * 32 + lane];
        ushort4 x6 = xb[s6 * 32 + lane];
        ushort4 x7 = xb[s7 * 32 + lane];
        float m1 = (r > 1) ? 1.f : 0.f;
        float m2 = (r > 2) ? 1.f : 0.f;
        float m3 = (r > 3) ? 1.f : 0.f;
        float m4 = (r > 4) ? 1.f : 0.f;
        float m5 = (r > 5) ? 1.f : 0.f;
        float m6 = (r > 6) ? 1.f : 0.f;
        float m7 = (r > 7) ? 1.f : 0.f;
        ax += bf2f(x0.x); ay += bf2f(x0.y); az += bf2f(x0.z); aw += bf2f(x0.w);
        ax += m1 * bf2f(x1.x); ay += m1 * bf2f(x1.y); az += m1 * bf2f(x1.z); aw += m1 * bf2f(x1.w);
        ax += m2 * bf2f(x2.x); ay += m2 * bf2f(x2.y); az += m2 * bf2f(x2.z); aw += m2 * bf2f(x2.w);
        ax += m3 * bf2f(x3.x); ay += m3 * bf2f(x3.y); az += m3 * bf2f(x3.z); aw += m3 * bf2f(x3.w);
        ax += m4 * bf2f(x4v.x); ay += m4 * bf2f(x4v.y); az += m4 * bf2f(x4v.z); aw += m4 * bf2f(x4v.w);
        ax += m5 * bf2f(x5.x); ay += m5 * bf2f(x5.y); az += m5 * bf2f(x5.z); aw += m5 * bf2f(x5.w);
        ax += m6 * bf2f(x6.x); ay += m6 * bf2f(x6.y); az += m6 * bf2f(x6.z); aw += m6 * bf2f(x6.w);
        ax += m7 * bf2f(x7.x); ay += m7 * bf2f(x7.y); az += m7 * bf2f(x7.z); aw += m7 * bf2f(x7.w);
    }
    ushort4 u;
    u.x = f2bf(ax); u.y = f2bf(ay); u.z = f2bf(az); u.w = f2bf(aw);
    hout[node * 32 + lane] = u;
}

// ---------------------------------------------------------------------------
// Persistent-W GEMM + bias + BN-stat accumulation (round-11/12/13 verified).
// Whole bf16 W in registers; grid-stride over 16-row tiles, prefetch depth 1;
// epilogue staged through wave-private LDS for fully-covered 128B-line
// stores. FUSE_BN=1: BN(statsIn)+ReLU applied to bf16 A in the loader.
// OUT_BF16=1: y stored as bf16 (half write traffic; stats stay exact fp32).
// ---------------------------------------------------------------------------
template <int FUSE_BN, int OUT_BF16>
__global__ __launch_bounds__(256, 2) void gin_gemm_k(
    const unsigned short* __restrict__ hin,
    const float* __restrict__ statsIn,
    const float* __restrict__ gmm,
    const float* __restrict__ bta,
    const unsigned short* __restrict__ Wbf, const float* __restrict__ bias,
    float* __restrict__ yf, unsigned short* __restrict__ yh,
    float* __restrict__ statsOut) {
    __shared__ __align__(16) float s_sum[128];
    __shared__ __align__(16) float s_sq[128];
    __shared__ __align__(16) float sc[128];
    __shared__ __align__(16) float sh[128];
    __shared__ __align__(16) float yst[4][16][132];  // fp32 tile (+4 pad)

    const int tid = threadIdx.x;
    const int l = tid & 63, w = tid >> 6;
    const int m = l & 15, q = l >> 4;

    if (tid < 128) {
        s_sum[tid] = 0.f;
        s_sq[tid] = 0.f;
        if (FUSE_BN) {
            const float inv = 1.0f / (float)NN;
            float mean = statsIn[tid] * inv;
            float var = statsIn[128 + tid] * inv - mean * mean;
            float s = gmm[tid] * rsqrtf(var + 1e-5f);
            sc[tid] = s;
            sh[tid] = bta[tid] - mean * s;
        }
    }

    // --- whole W into registers, once per wave ---
    bf16x8 wf[8][4];
#pragma unroll
    for (int ct = 0; ct < 8; ++ct) {
        const unsigned short* wr = Wbf + (size_t)(ct * 16 + m) * 128 + q * 8;
#pragma unroll
        for (int kc = 0; kc < 4; ++kc) {
            BF8 t;
            t.i4 = *(const int4*)(wr + kc * 32);
            wf[ct][kc] = t.v;
        }
    }
    float bc[8];
#pragma unroll
    for (int ct = 0; ct < 8; ++ct) bc[ct] = bias[ct * 16 + m];

    float ps[8], pq[8];
#pragma unroll
    for (int ct = 0; ct < 8; ++ct) { ps[ct] = 0.f; pq[ct] = 0.f; }

    __syncthreads();  // s_sum/s_sq (and sc/sh) visible

    const int NT = NN / 16;              // 6250, exact
    const int stride = gridDim.x * 4;    // waves total
    int t = blockIdx.x * 4 + w;

    const unsigned short* abase = hin + (size_t)m * 128 + q * 8;

    int4 ra[4];
    if (t < NT) {
        const unsigned short* ap = abase + (size_t)t * (16 * 128);
#pragma unroll
        for (int kc = 0; kc < 4; ++kc) ra[kc] = *(const int4*)(ap + kc * 32);
    }

    // bf16 store path aliases this wave's fp32 tile region: 16 x [144] ushort
    unsigned short* ysth = (unsigned short*)&yst[w][0][0];

    while (t < NT) {
        bf16x8 a[4];
#pragma unroll
        for (int kc = 0; kc < 4; ++kc) {
            if (FUSE_BN) {
                BF8 raw;
                raw.i4 = ra[kc];
                const float* scp = sc + kc * 32 + q * 8;
                const float* shp = sh + kc * 32 + q * 8;
                float4 s0 = *(const float4*)scp;
                float4 s1 = *(const float4*)(scp + 4);
                float4 h0 = *(const float4*)shp;
                float4 h1 = *(const float4*)(shp + 4);
                BF8 tt;
                tt.u[0] = f2bf(fmaxf(bf2f(raw.u[0]) * s0.x + h0.x, 0.f));
                tt.u[1] = f2bf(fmaxf(bf2f(raw.u[1]) * s0.y + h0.y, 0.f));
                tt.u[2] = f2bf(fmaxf(bf2f(raw.u[2]) * s0.z + h0.z, 0.f));
                tt.u[3] = f2bf(fmaxf(bf2f(raw.u[3]) * s0.w + h0.w, 0.f));
                tt.u[4] = f2bf(fmaxf(bf2f(raw.u[4]) * s1.x + h1.x, 0.f));
                tt.u[5] = f2bf(fmaxf(bf2f(raw.u[5]) * s1.y + h1.y, 0.f));
                tt.u[6] = f2bf(fmaxf(bf2f(raw.u[6]) * s1.z + h1.z, 0.f));
                tt.u[7] = f2bf(fmaxf(bf2f(raw.u[7]) * s1.w + h1.w, 0.f));
                a[kc] = tt.v;
            } else {
                BF8 tt;
                tt.i4 = ra[kc];
                a[kc] = tt.v;
            }
        }

        int tn = t + stride;
        if (tn < NT) {
            const unsigned short* ap = abase + (size_t)tn * (16 * 128);
#pragma unroll
            for (int kc = 0; kc < 4; ++kc) ra[kc] = *(const int4*)(ap + kc * 32);
        }

        floatx4 acc[8];
#pragma unroll
        for (int ct = 0; ct < 8; ++ct) acc[ct] = (floatx4)0.0f;
#pragma unroll
        for (int kc = 0; kc < 4; ++kc)
#pragma unroll
            for (int ct = 0; ct < 8; ++ct)
                acc[ct] = __builtin_amdgcn_mfma_f32_16x16x32_bf16(a[kc], wf[ct][kc], acc[ct], 0, 0, 0);

        // epilogue: bias + stats (exact fp32), stage tile in wave-private
        // LDS, then store full contiguous rows (fully covered 128B lines)
#pragma unroll
        for (int ct = 0; ct < 8; ++ct) {
#pragma unroll
            for (int i = 0; i < 4; ++i) {
                float yv = acc[ct][i] + bc[ct];
                if (OUT_BF16) {
                    ysth[(q * 4 + i) * 144 + ct * 16 + m] = f2bf(yv);
                } else {
                    yst[w][q * 4 + i][ct * 16 + m] = yv;
                }
                ps[ct] += yv;
                pq[ct] += yv * yv;
            }
        }
        asm volatile("s_waitcnt lgkmcnt(0)" ::: "memory");
        if (OUT_BF16) {
            unsigned short* yb = yh + (size_t)t * (16 * 128);
#pragma unroll
            for (int it = 0; it < 4; ++it) {
                int f = it * 64 + l;
                int row = f >> 4, c8 = f & 15;   // 16 x 16B units per row
                int4 vv = *(const int4*)&ysth[row * 144 + c8 * 8];
                *(int4*)(yb + row * 128 + c8 * 8) = vv;
            }
        } else {
            float* yb = yf + (size_t)t * (16 * 128);
#pragma unroll
            for (int it = 0; it < 8; ++it) {
                int f4 = it * 64 + l;
                int row = f4 >> 5, c4 = f4 & 31;
                float4 vv = *(const float4*)&yst[w][row][c4 * 4];
                *(float4*)(yb + row * 128 + c4 * 4) = vv;
            }
        }
        t = tn;
    }

    // flush register stats: LDS reduce, then 2 global atomics per column
#pragma unroll
    for (int ct = 0; ct < 8; ++ct) {
        atomicAdd(&s_sum[ct * 16 + m], ps[ct]);
        atomicAdd(&s_sq[ct * 16 + m], pq[ct]);
    }
    __syncthreads();
    if (tid < 128) {
        unsafeAtomicAdd(&statsOut[tid], s_sum[tid]);
        unsafeAtomicAdd(&statsOut[128 + tid], s_sq[tid]);
    }
}

// ---------------------------------------------------------------------------
// BN(train, biased var) + ReLU, fp32 in place (final layer only).
// ---------------------------------------------------------------------------
__global__ __launch_bounds__(256) void bn_relu_k(
    const float* __restrict__ y, const float* __restrict__ stats,
    const float* __restrict__ g, const float* __restrict__ beta,
    float* __restrict__ outf) {
    __shared__ __align__(16) float sc[128];
    __shared__ __align__(16) float sh[128];
    int t = threadIdx.x;
    if (t < 128) {
        const float inv = 1.0f / (float)NN;
        float mean = stats[t] * inv;
        float var = stats[128 + t] * inv - mean * mean;
        float s = g[t] * rsqrtf(var + 1e-5f);
        sc[t] = s;
        sh[t] = beta[t] - mean * s;
    }
    __syncthreads();
    const int total4 = NN * 32;
    const float4* y4 = (const float4*)y;
    for (int i = blockIdx.x * 256 + t; i < total4; i += gridDim.x * 256) {
        int c4 = i & 31;
        float4 v = y4[i];
        float4 s = ((const float4*)sc)[c4];
        float4 b = ((const float4*)sh)[c4];
        float r0 = fmaxf(v.x * s.x + b.x, 0.f);
        float r1 = fmaxf(v.y * s.y + b.y, 0.f);
        float r2 = fmaxf(v.z * s.z + b.z, 0.f);
        float r3 = fmaxf(v.w * s.w + b.w, 0.f);
        ((float4*)outf)[i] = make_float4(r0, r1, r2, r3);
    }
}

// ---------------------------------------------------------------------------
extern "C" void kernel_launch(void* const* d_in, const int* in_sizes, int n_in,
                              void* d_out, int out_size, void* d_ws, size_t ws_size,
                              hipStream_t stream) {
    const float* x   = (const float*)d_in[0];
    const int* ei    = (const int*)d_in[1];   // int64 in ref -> int32 from harness
    const float* eps = (const float*)d_in[2];
    const float* W1  = (const float*)d_in[3];
    const float* b1  = (const float*)d_in[4];
    const float* g1  = (const float*)d_in[5];
    const float* be1 = (const float*)d_in[6];
    const float* W2  = (const float*)d_in[7];
    const float* b2  = (const float*)d_in[8];
    const float* g2  = (const float*)d_in[9];
    const float* be2 = (const float*)d_in[10];
    float* out = (float*)d_out;

    // Workspace (~61 MB):
    // [degr NREP*NPAD][descr 512][offs NPAD][curr NREP*NPAD][ssrc EE+256]
    // [hbuf bf16 25.6MB][y1bf/xbf bf16 25.6MB (aliased: xbf dies at
    //  aggregate, y1bf born at gemm1)][stats 512f][wbf 2*128*128 bf16]
    int* degr           = (int*)d_ws;                       // NREP*NPAD
    unsigned int* descr = (unsigned int*)(degr + NREP * NPAD);  // 512
    int* offs           = (int*)(descr + 512);
    int* curr           = offs + NPAD;                      // NREP*NPAD
    int* ssrc           = curr + NREP * NPAD;
    unsigned short* hbuf = (unsigned short*)(ssrc + EE + 256);
    unsigned short* y1bf = hbuf + (size_t)NN * DD;   // also xbf
    float* stats        = (float*)(y1bf + (size_t)NN * DD);
    unsigned short* wbf = (unsigned short*)(stats + 512);
    ushort4* xbf        = (ushort4*)y1bf;

    // one memset covers degr replicas + lookback descriptors (adjacent)
    hipMemsetAsync(degr, 0, (NREP * NPAD + 512) * sizeof(int), stream);

    hist_k<<<2500, 256, 0, stream>>>(ei, degr);
    convert_k<<<3125, 256, 0, stream>>>((const float4*)x, xbf);
    scanlb_k<<<NCHUNK, 256, 0, stream>>>(degr, descr, offs, curr);
    esort_k<<<2500 + 32, 256, 0, stream>>>(ei, curr, ssrc, W1, W2, wbf, stats);
    aggregate_k<<<(NN * 32 + 255) / 256, 256, 0, stream>>>(
        xbf, ssrc, offs, degr, eps, (ushort4*)hbuf);

    const int gblocks = 512;  // ~2 blocks/CU, persistent grid-stride
    // gemm1: h(bf16) @ W1^T -> y1 as bf16 (+exact fp32 stats1)
    gin_gemm_k<0, 1><<<gblocks, 256, 0, stream>>>(
        hbuf, nullptr, nullptr, nullptr, wbf, b1, nullptr, y1bf, stats);
    // gemm2: BN1(y1bf)+ReLU in loader, @ W2^T -> y2 fp32 to out (+stats2)
    gin_gemm_k<1, 0><<<gblocks, 256, 0, stream>>>(
        y1bf, stats, g1, be1, wbf + 16384, b2, out, nullptr, stats + 256);
    bn_relu_k<<<4096, 256, 0, stream>>>(out, stats + 256, g2, be2, out);
}

// Round 16
// 305.986 us; speedup vs baseline: 1.0144x; 1.0144x over previous
//
#include <hip/hip_runtime.h>

#define NN 100000
#define DD 128
#define EE 640000
#define NPAD 100352   // NN rounded up to 256 multiple
#define NCHUNK 391    // (NN+255)/256
#define NREP 8        // histogram/cursor replicas

typedef __bf16 bf16x8 __attribute__((ext_vector_type(8)));
typedef float floatx4 __attribute__((ext_vector_type(4)));

union BF8 {
    bf16x8 v;
    unsigned short u[8];
    int4 i4;
};

__device__ __forceinline__ unsigned short f2bf(float f) {
    unsigned int u = __float_as_uint(f);
    u += 0x7FFF + ((u >> 16) & 1);   // round-to-nearest-even
    return (unsigned short)(u >> 16);
}

__device__ __forceinline__ float bf2f(unsigned short h) {
    return __uint_as_float(((unsigned int)h) << 16);
}

// ---------------------------------------------------------------------------
// Pure degree histogram, NREP-replicated (replica = blockIdx & 7).
// ---------------------------------------------------------------------------
__global__ __launch_bounds__(256) void hist_k(const int* __restrict__ ei,
                                              int* __restrict__ degr) {
    int e = blockIdx.x * 256 + threadIdx.x;       // EE = 2500*256 exactly
    atomicAdd(&degr[(blockIdx.x & (NREP - 1)) * NPAD + ei[EE + e]], 1);
}

// Single-pass exclusive scan over NN total degrees (sum of NREP replicas);
// precomputes per-replica cursor bases (esort uses the same block&7 mapping,
// so per-replica slot counts match exactly). Wave-parallel lookback
// (round-8 lesson: single-thread walk = 106us serial chain).
__global__ __launch_bounds__(256) void scanlb_k(
    int* __restrict__ degr, unsigned int* __restrict__ descr,
    int* __restrict__ offs, int* __restrict__ curr) {
    __shared__ int s[256];
    __shared__ int sbase;
    const int c = blockIdx.x, t = threadIdx.x;
    int g = c * 256 + t;
    int dr[NREP];
    int v = 0;
    if (g < NN) {
#pragma unroll
        for (int r = 0; r < NREP; ++r) {
            dr[r] = degr[r * NPAD + g];
            v += dr[r];
        }
    } else {
#pragma unroll
        for (int r = 0; r < NREP; ++r) dr[r] = 0;
    }
    s[t] = v;
    __syncthreads();
    for (int off = 1; off < 256; off <<= 1) {
        int u = (t >= off) ? s[t - off] : 0;
        __syncthreads();
        s[t] += u;
        __syncthreads();
    }
    const int total = s[255];
    if (c == 0) {
        if (t == 0) {
            __hip_atomic_store(&descr[0], (2u << 30) | (unsigned)total,
                               __ATOMIC_RELEASE, __HIP_MEMORY_SCOPE_AGENT);
            sbase = 0;
        }
    } else if (t < 64) {
        if (t == 0)
            __hip_atomic_store(&descr[c], (1u << 30) | (unsigned)total,
                               __ATOMIC_RELEASE, __HIP_MEMORY_SCOPE_AGENT);
        int acc = 0;
        int base = c - 1;              // lane l inspects block (base - l)
        while (true) {
            int p = base - t;
            unsigned st = (p >= 0)
                ? __hip_atomic_load(&descr[p], __ATOMIC_ACQUIRE,
                                    __HIP_MEMORY_SCOPE_AGENT)
                : (2u << 30);          // virtual block -1: prefix 0
            unsigned fl = st >> 30;
            unsigned long long b2 = __ballot(fl == 2u);
            unsigned long long b0 = __ballot(fl == 0u);
            int l2 = b2 ? (__ffsll(b2) - 1) : 64;   // nearest inclusive-prefix
            int l0 = b0 ? (__ffsll(b0) - 1) : 64;   // nearest unpublished
            if (l0 < l2) continue;     // blocked by an empty slot: retry
            unsigned contrib = (t <= l2) ? (st & 0x3FFFFFFFu) : 0u;
#pragma unroll
            for (int o2 = 32; o2 > 0; o2 >>= 1)
                contrib += __shfl_down(contrib, o2, 64);
            contrib = __shfl(contrib, 0, 64);
            acc += (int)contrib;
            if (l2 < 64) break;        // absorbed an inclusive prefix
            base -= 64;                // all aggregates: step back a window
        }
        if (t == 0) {
            sbase = acc;
            __hip_atomic_store(&descr[c], (2u << 30) | (unsigned)(acc + total),
                               __ATOMIC_RELEASE, __HIP_MEMORY_SCOPE_AGENT);
        }
    }
    __syncthreads();
    if (g < NN) {
        int o = sbase + s[t] - v;   // exclusive prefix
        offs[g] = o;
        int running = o;
#pragma unroll
        for (int r = 0; r < NREP; ++r) {
            curr[r * NPAD + g] = running;
            running += dr[r];
        }
        degr[g] = v;   // total degree for aggregate (replica-0 slot reused)
    }
}

// esort (blocks 0..2499; replica = b&7 matches hist) + W fp32->bf16
// preconvert and stats zeroing (blocks 2500..2531) + x fp32->bf16 convert
// (blocks 2532..5656; 3125 blocks x 1024 float4 units = 3.2M exactly;
// 4 independent load/store pairs per thread for MLP).
__global__ __launch_bounds__(256) void esort_k(
    const int* __restrict__ ei, int* __restrict__ curr,
    int* __restrict__ ssrc, const float* __restrict__ W1,
    const float* __restrict__ W2, unsigned short* __restrict__ wbf,
    float* __restrict__ stats, const float4* __restrict__ x4,
    ushort4* __restrict__ xbf) {
    int b = blockIdx.x;
    if (b >= 2532) {
        int base = (b - 2532) * 1024 + threadIdx.x;
        float4 v0 = x4[base];
        float4 v1 = x4[base + 256];
        float4 v2 = x4[base + 512];
        float4 v3 = x4[base + 768];
        ushort4 u0, u1, u2, u3;
        u0.x = f2bf(v0.x); u0.y = f2bf(v0.y); u0.z = f2bf(v0.z); u0.w = f2bf(v0.w);
        u1.x = f2bf(v1.x); u1.y = f2bf(v1.y); u1.z = f2bf(v1.z); u1.w = f2bf(v1.w);
        u2.x = f2bf(v2.x); u2.y = f2bf(v2.y); u2.z = f2bf(v2.z); u2.w = f2bf(v2.w);
        u3.x = f2bf(v3.x); u3.y = f2bf(v3.y); u3.z = f2bf(v3.z); u3.w = f2bf(v3.w);
        xbf[base] = u0;
        xbf[base + 256] = u1;
        xbf[base + 512] = u2;
        xbf[base + 768] = u3;
        return;
    }
    if (b >= 2500) {
        int i = (b - 2500) * 256 + threadIdx.x;   // 0..8191 float4 units
        if (b == 2500) {
            stats[threadIdx.x] = 0.f;
            stats[256 + threadIdx.x] = 0.f;
        }
        const float4* s4 = (i < 4096) ? (const float4*)W1 : (const float4*)W2;
        float4 v = s4[i & 4095];
        ushort4 u;
        u.x = f2bf(v.x); u.y = f2bf(v.y); u.z = f2bf(v.z); u.w = f2bf(v.w);
        ((ushort4*)wbf)[i] = u;
        return;
    }
    int e = b * 256 + threadIdx.x;
    int pos = atomicAdd(&curr[(b & (NREP - 1)) * NPAD + ei[EE + e]], 1);
    ssrc[pos] = ei[e];
}

// ---------------------------------------------------------------------------
// aggregate + fuse: h[node] = bf16((1+eps)*x[node] + sum_{src in CSR} x[src])
// Gathers from the bf16 x copy (256B rows, 25.6MB working set); 8-wide
// predicated unroll; 12500 independent blocks.
// ---------------------------------------------------------------------------
__global__ __launch_bounds__(256, 4) void aggregate_k(
    const ushort4* __restrict__ xb, const int* __restrict__ ssrc,
    const int* __restrict__ offs, const int* __restrict__ deg,
    const float* __restrict__ epsp, ushort4* __restrict__ hout) {
    int tid = blockIdx.x * 256 + threadIdx.x;
    int node = tid >> 5, lane = tid & 31;
    if (node >= NN) return;
    int start = offs[node], d = deg[node];
    float ef = 1.0f + epsp[0];
    ushort4 ov = xb[node * 32 + lane];
    float ax = ef * bf2f(ov.x), ay = ef * bf2f(ov.y);
    float az = ef * bf2f(ov.z), aw = ef * bf2f(ov.w);
    for (int j = 0; j < d; j += 8) {
        int r = d - j;          // >= 1
        int b = start + j;
        int s0 = ssrc[b];
        int s1 = ssrc[b + ((r > 1) ? 1 : 0)];
        int s2 = ssrc[b + ((r > 2) ? 2 : 0)];
        int s3 = ssrc[b + ((r > 3) ? 3 : 0)];
        int s4i = ssrc[b + ((r > 4) ? 4 : 0)];
        int s5 = ssrc[b + ((r > 5) ? 5 : 0)];
        int s6 = ssrc[b + ((r > 6) ? 6 : 0)];
        int s7 = ssrc[b + ((r > 7) ? 7 : 0)];
        ushort4 x0 = xb[s0 * 32 + lane];
        ushort4 x1 = xb[s1 * 32 + lane];
        ushort4 x2 = xb[s2 * 32 + lane];
        ushort4 x3 = xb[s3 * 32 + lane];
        ushort4 x4v = xb[s4i * 32 + lane];
        ushort4 x5 = xb[s5 * 32 + lane];
        ushort4 x6 = xb[s6 * 32 + lane];
        ushort4 x7 = xb[s7 * 32 + lane];
        float m1 = (r > 1) ? 1.f : 0.f;
        float m2 = (r > 2) ? 1.f : 0.f;
        float m3 = (r > 3) ? 1.f : 0.f;
        float m4 = (r > 4) ? 1.f : 0.f;
        float m5 = (r > 5) ? 1.f : 0.f;
        float m6 = (r > 6) ? 1.f : 0.f;
        float m7 = (r > 7) ? 1.f : 0.f;
        ax += bf2f(x0.x); ay += bf2f(x0.y); az += bf2f(x0.z); aw += bf2f(x0.w);
        ax += m1 * bf2f(x1.x); ay += m1 * bf2f(x1.y); az += m1 * bf2f(x1.z); aw += m1 * bf2f(x1.w);
        ax += m2 * bf2f(x2.x); ay += m2 * bf2f(x2.y); az += m2 * bf2f(x2.z); aw += m2 * bf2f(x2.w);
        ax += m3 * bf2f(x3.x); ay += m3 * bf2f(x3.y); az += m3 * bf2f(x3.z); aw += m3 * bf2f(x3.w);
        ax += m4 * bf2f(x4v.x); ay += m4 * bf2f(x4v.y); az += m4 * bf2f(x4v.z); aw += m4 * bf2f(x4v.w);
        ax += m5 * bf2f(x5.x); ay += m5 * bf2f(x5.y); az += m5 * bf2f(x5.z); aw += m5 * bf2f(x5.w);
        ax += m6 * bf2f(x6.x); ay += m6 * bf2f(x6.y); az += m6 * bf2f(x6.z); aw += m6 * bf2f(x6.w);
        ax += m7 * bf2f(x7.x); ay += m7 * bf2f(x7.y); az += m7 * bf2f(x7.z); aw += m7 * bf2f(x7.w);
    }
    ushort4 u;
    u.x = f2bf(ax); u.y = f2bf(ay); u.z = f2bf(az); u.w = f2bf(aw);
    hout[node * 32 + lane] = u;
}

// ---------------------------------------------------------------------------
// Persistent-W GEMM + bias + BN-stat accumulation (rounds 11-14 verified).
// Whole bf16 W in registers; grid-stride over 16-row tiles, prefetch depth 1;
// epilogue staged through wave-private LDS for fully-covered 128B-line
// stores. FUSE_BN=1: BN(statsIn)+ReLU applied to bf16 A in the loader.
// OUT_BF16=1: y stored as bf16 (half write traffic; stats stay exact fp32).
// ---------------------------------------------------------------------------
template <int FUSE_BN, int OUT_BF16>
__global__ __launch_bounds__(256, 2) void gin_gemm_k(
    const unsigned short* __restrict__ hin,
    const float* __restrict__ statsIn,
    const float* __restrict__ gmm,
    const float* __restrict__ bta,
    const unsigned short* __restrict__ Wbf, const float* __restrict__ bias,
    float* __restrict__ yf, unsigned short* __restrict__ yh,
    float* __restrict__ statsOut) {
    __shared__ __align__(16) float s_sum[128];
    __shared__ __align__(16) float s_sq[128];
    __shared__ __align__(16) float sc[128];
    __shared__ __align__(16) float sh[128];
    __shared__ __align__(16) float yst[4][16][132];  // fp32 tile (+4 pad)

    const int tid = threadIdx.x;
    const int l = tid & 63, w = tid >> 6;
    const int m = l & 15, q = l >> 4;

    if (tid < 128) {
        s_sum[tid] = 0.f;
        s_sq[tid] = 0.f;
        if (FUSE_BN) {
            const float inv = 1.0f / (float)NN;
            float mean = statsIn[tid] * inv;
            float var = statsIn[128 + tid] * inv - mean * mean;
            float s = gmm[tid] * rsqrtf(var + 1e-5f);
            sc[tid] = s;
            sh[tid] = bta[tid] - mean * s;
        }
    }

    // --- whole W into registers, once per wave ---
    bf16x8 wf[8][4];
#pragma unroll
    for (int ct = 0; ct < 8; ++ct) {
        const unsigned short* wr = Wbf + (size_t)(ct * 16 + m) * 128 + q * 8;
#pragma unroll
        for (int kc = 0; kc < 4; ++kc) {
            BF8 t;
            t.i4 = *(const int4*)(wr + kc * 32);
            wf[ct][kc] = t.v;
        }
    }
    float bc[8];
#pragma unroll
    for (int ct = 0; ct < 8; ++ct) bc[ct] = bias[ct * 16 + m];

    float ps[8], pq[8];
#pragma unroll
    for (int ct = 0; ct < 8; ++ct) { ps[ct] = 0.f; pq[ct] = 0.f; }

    __syncthreads();  // s_sum/s_sq (and sc/sh) visible

    const int NT = NN / 16;              // 6250, exact
    const int stride = gridDim.x * 4;    // waves total
    int t = blockIdx.x * 4 + w;

    const unsigned short* abase = hin + (size_t)m * 128 + q * 8;

    int4 ra[4];
    if (t < NT) {
        const unsigned short* ap = abase + (size_t)t * (16 * 128);
#pragma unroll
        for (int kc = 0; kc < 4; ++kc) ra[kc] = *(const int4*)(ap + kc * 32);
    }

    // bf16 store path aliases this wave's fp32 tile region: 16 x [144] ushort
    unsigned short* ysth = (unsigned short*)&yst[w][0][0];

    while (t < NT) {
        bf16x8 a[4];
#pragma unroll
        for (int kc = 0; kc < 4; ++kc) {
            if (FUSE_BN) {
                BF8 raw;
                raw.i4 = ra[kc];
                const float* scp = sc + kc * 32 + q * 8;
                const float* shp = sh + kc * 32 + q * 8;
                float4 s0 = *(const float4*)scp;
                float4 s1 = *(const float4*)(scp + 4);
                float4 h0 = *(const float4*)shp;
                float4 h1 = *(const float4*)(shp + 4);
                BF8 tt;
                tt.u[0] = f2bf(fmaxf(bf2f(raw.u[0]) * s0.x + h0.x, 0.f));
                tt.u[1] = f2bf(fmaxf(bf2f(raw.u[1]) * s0.y + h0.y, 0.f));
                tt.u[2] = f2bf(fmaxf(bf2f(raw.u[2]) * s0.z + h0.z, 0.f));
                tt.u[3] = f2bf(fmaxf(bf2f(raw.u[3]) * s0.w + h0.w, 0.f));
                tt.u[4] = f2bf(fmaxf(bf2f(raw.u[4]) * s1.x + h1.x, 0.f));
                tt.u[5] = f2bf(fmaxf(bf2f(raw.u[5]) * s1.y + h1.y, 0.f));
                tt.u[6] = f2bf(fmaxf(bf2f(raw.u[6]) * s1.z + h1.z, 0.f));
                tt.u[7] = f2bf(fmaxf(bf2f(raw.u[7]) * s1.w + h1.w, 0.f));
                a[kc] = tt.v;
            } else {
                BF8 tt;
                tt.i4 = ra[kc];
                a[kc] = tt.v;
            }
        }

        int tn = t + stride;
        if (tn < NT) {
            const unsigned short* ap = abase + (size_t)tn * (16 * 128);
#pragma unroll
            for (int kc = 0; kc < 4; ++kc) ra[kc] = *(const int4*)(ap + kc * 32);
        }

        floatx4 acc[8];
#pragma unroll
        for (int ct = 0; ct < 8; ++ct) acc[ct] = (floatx4)0.0f;
#pragma unroll
        for (int kc = 0; kc < 4; ++kc)
#pragma unroll
            for (int ct = 0; ct < 8; ++ct)
                acc[ct] = __builtin_amdgcn_mfma_f32_16x16x32_bf16(a[kc], wf[ct][kc], acc[ct], 0, 0, 0);

        // epilogue: bias + stats (exact fp32), stage tile in wave-private
        // LDS, then store full contiguous rows (fully covered 128B lines)
#pragma unroll
        for (int ct = 0; ct < 8; ++ct) {
#pragma unroll
            for (int i = 0; i < 4; ++i) {
                float yv = acc[ct][i] + bc[ct];
                if (OUT_BF16) {
                    ysth[(q * 4 + i) * 144 + ct * 16 + m] = f2bf(yv);
                } else {
                    yst[w][q * 4 + i][ct * 16 + m] = yv;
                }
                ps[ct] += yv;
                pq[ct] += yv * yv;
            }
        }
        asm volatile("s_waitcnt lgkmcnt(0)" ::: "memory");
        if (OUT_BF16) {
            unsigned short* yb = yh + (size_t)t * (16 * 128);
#pragma unroll
            for (int it = 0; it < 4; ++it) {
                int f = it * 64 + l;
                int row = f >> 4, c8 = f & 15;   // 16 x 16B units per row
                int4 vv = *(const int4*)&ysth[row * 144 + c8 * 8];
                *(int4*)(yb + row * 128 + c8 * 8) = vv;
            }
        } else {
            float* yb = yf + (size_t)t * (16 * 128);
#pragma unroll
            for (int it = 0; it < 8; ++it) {
                int f4 = it * 64 + l;
                int row = f4 >> 5, c4 = f4 & 31;
                float4 vv = *(const float4*)&yst[w][row][c4 * 4];
                *(float4*)(yb + row * 128 + c4 * 4) = vv;
            }
        }
        t = tn;
    }

    // flush register stats: LDS reduce, then 2 global atomics per column
#pragma unroll
    for (int ct = 0; ct < 8; ++ct) {
        atomicAdd(&s_sum[ct * 16 + m], ps[ct]);
        atomicAdd(&s_sq[ct * 16 + m], pq[ct]);
    }
    __syncthreads();
    if (tid < 128) {
        unsafeAtomicAdd(&statsOut[tid], s_sum[tid]);
        unsafeAtomicAdd(&statsOut[128 + tid], s_sq[tid]);
    }
}

// ---------------------------------------------------------------------------
// BN(train, biased var) + ReLU: reads bf16 y2, writes fp32 out.
// (Stats are exact fp32 from the gemm; y2's bf16 rounding is renormalized.)
// ---------------------------------------------------------------------------
__global__ __launch_bounds__(256) void bn_relu_k(
    const ushort4* __restrict__ yh, const float* __restrict__ stats,
    const float* __restrict__ g, const float* __restrict__ beta,
    float4* __restrict__ outf) {
    __shared__ __align__(16) float sc[128];
    __shared__ __align__(16) float sh[128];
    int t = threadIdx.x;
    if (t < 128) {
        const float inv = 1.0f / (float)NN;
        float mean = stats[t] * inv;
        float var = stats[128 + t] * inv - mean * mean;
        float s = g[t] * rsqrtf(var + 1e-5f);
        sc[t] = s;
        sh[t] = beta[t] - mean * s;
    }
    __syncthreads();
    const int total4 = NN * 32;
    for (int i = blockIdx.x * 256 + t; i < total4; i += gridDim.x * 256) {
        int c4 = i & 31;
        ushort4 v = yh[i];
        float4 s = ((const float4*)sc)[c4];
        float4 b = ((const float4*)sh)[c4];
        float r0 = fmaxf(bf2f(v.x) * s.x + b.x, 0.f);
        float r1 = fmaxf(bf2f(v.y) * s.y + b.y, 0.f);
        float r2 = fmaxf(bf2f(v.z) * s.z + b.z, 0.f);
        float r3 = fmaxf(bf2f(v.w) * s.w + b.w, 0.f);
        outf[i] = make_float4(r0, r1, r2, r3);
    }
}

// ---------------------------------------------------------------------------
extern "C" void kernel_launch(void* const* d_in, const int* in_sizes, int n_in,
                              void* d_out, int out_size, void* d_ws, size_t ws_size,
                              hipStream_t stream) {
    const float* x   = (const float*)d_in[0];
    const int* ei    = (const int*)d_in[1];   // int64 in ref -> int32 from harness
    const float* eps = (const float*)d_in[2];
    const float* W1  = (const float*)d_in[3];
    const float* b1  = (const float*)d_in[4];
    const float* g1  = (const float*)d_in[5];
    const float* be1 = (const float*)d_in[6];
    const float* W2  = (const float*)d_in[7];
    const float* b2  = (const float*)d_in[8];
    const float* g2  = (const float*)d_in[9];
    const float* be2 = (const float*)d_in[10];
    float* out = (float*)d_out;

    // Workspace (~61 MB):
    // [degr NREP*NPAD][descr 512][offs NPAD][curr NREP*NPAD][ssrc EE+256]
    // [hbuf bf16 25.6MB (h for gemm1; y2bf for gemm2/bn_relu — h dead then)]
    // [y1bf/xbf bf16 25.6MB (xbf dies at aggregate, y1bf born at gemm1)]
    // [stats 512f][wbf 2*128*128 bf16]
    int* degr           = (int*)d_ws;                       // NREP*NPAD
    unsigned int* descr = (unsigned int*)(degr + NREP * NPAD);  // 512
    int* offs           = (int*)(descr + 512);
    int* curr           = offs + NPAD;                      // NREP*NPAD
    int* ssrc           = curr + NREP * NPAD;
    unsigned short* hbuf = (unsigned short*)(ssrc + EE + 256);
    unsigned short* y1bf = hbuf + (size_t)NN * DD;   // also xbf
    float* stats        = (float*)(y1bf + (size_t)NN * DD);
    unsigned short* wbf = (unsigned short*)(stats + 512);
    ushort4* xbf        = (ushort4*)y1bf;

    // one memset covers degr replicas + lookback descriptors (adjacent)
    hipMemsetAsync(degr, 0, (NREP * NPAD + 512) * sizeof(int), stream);

    hist_k<<<2500, 256, 0, stream>>>(ei, degr);
    scanlb_k<<<NCHUNK, 256, 0, stream>>>(degr, descr, offs, curr);
    // esort + W convert + stats zero + x->bf16 convert, one dispatch
    esort_k<<<2500 + 32 + 3125, 256, 0, stream>>>(
        ei, curr, ssrc, W1, W2, wbf, stats, (const float4*)x, xbf);
    aggregate_k<<<(NN * 32 + 255) / 256, 256, 0, stream>>>(
        xbf, ssrc, offs, degr, eps, (ushort4*)hbuf);

    const int gblocks = 512;  // ~2 blocks/CU, persistent grid-stride
    // gemm1: h(bf16) @ W1^T -> y1 as bf16 (+exact fp32 stats1)
    gin_gemm_k<0, 1><<<gblocks, 256, 0, stream>>>(
        hbuf, nullptr, nullptr, nullptr, wbf, b1, nullptr, y1bf, stats);
    // gemm2: BN1(y1bf)+ReLU in loader, @ W2^T -> y2 as bf16 into hbuf
    // (h is dead after gemm1; y1bf/hbuf disjoint) (+exact fp32 stats2)
    gin_gemm_k<1, 1><<<gblocks, 256, 0, stream>>>(
        y1bf, stats, g1, be1, wbf + 16384, b2, nullptr, hbuf, stats + 256);
    // BN2+ReLU: bf16 y2 -> fp32 out
    bn_relu_k<<<4096, 256, 0, stream>>>(
        (const ushort4*)hbuf, stats + 256, g2, be2, (float4*)out);
}